// Round 1
// baseline (1625.449 us; speedup 1.0000x reference)
//
#include <hip/hip_runtime.h>
#include <cstdint>
#include <cstddef>

// Problem constants (from reference)
#define L_   256
#define Q_   21
#define M_   8192
#define QQ   441          // Q*Q
#define ROWP 24           // padded row stride (floats) inside a transposed (i,j) block
#define BLKF (Q_ * ROWP)  // 504 floats per transposed block

// ws layout:
//   [0   .. 63 ]  float accumulators: [0]=wsum [1]=ll_sum [2]=h2_sum [3]=J2_sum
//   [256 .. +8MiB) seqsT  (L*M int32)
//   [256+8MiB ..)  Jt     (L*L*BLKF floats, only j<i blocks valid)

__device__ __forceinline__ float block_reduce_sum(float v) {
    __shared__ float s[256];
    int t = threadIdx.x;
    s[t] = v;
    __syncthreads();
#pragma unroll
    for (int o = 128; o > 0; o >>= 1) {
        if (t < o) s[t] += s[t + o];
        __syncthreads();
    }
    return s[0];
}

// ---- weights sum + h^2 sum (single block) ----
__global__ void k_wsum_h2(const float* __restrict__ w, const float* __restrict__ h,
                          float* __restrict__ acc) {
    int t = threadIdx.x;
    float v = 0.f;
    for (int x = t; x < M_; x += 256) v += w[x];
    float r = block_reduce_sum(v);
    if (t == 0) acc[0] = r;
    float v2 = 0.f;
    for (int x = t; x < L_ * Q_; x += 256) { float y = h[x]; v2 += y * y; }
    float r2 = block_reduce_sum(v2);
    if (t == 0) acc[2] = r2;
}

// ---- masked sum of J^2 over j<i ----
__global__ void k_regJ(const float* __restrict__ J, float* __restrict__ acc) {
    const int n = L_ * L_ * QQ;
    float v = 0.f;
    for (int idx = blockIdx.x * 256 + threadIdx.x; idx < n; idx += gridDim.x * 256) {
        int ij = idx / QQ;
        int j = ij & (L_ - 1);
        int i = ij >> 8;  // L_=256
        if (j < i) { float x = J[idx]; v += x * x; }
    }
    float r = block_reduce_sum(v);
    if (threadIdx.x == 0) atomicAdd(&acc[3], r);
}

// ---- seqs (M,L) -> seqsT (L,M) ----
__global__ void k_transpose_seqs(const int* __restrict__ seqs, int* __restrict__ seqsT) {
    int j = blockIdx.x;  // one block per position j
    for (int b = threadIdx.x; b < M_; b += 256) {
        seqsT[j * M_ + b] = seqs[b * L_ + j];
    }
}

// ---- J (i,j,a,k) -> Jt (i,j,k,a) with row padding, only j<i ----
__global__ void k_transpose_J(const float* __restrict__ J, float* __restrict__ Jt) {
    unsigned idx = blockIdx.x * 256u + threadIdx.x;
    const unsigned n = (unsigned)L_ * L_ * QQ;
    if (idx >= n) return;
    unsigned e  = idx % QQ;
    unsigned ij = idx / QQ;
    unsigned j = ij & (L_ - 1);
    unsigned i = ij >> 8;
    if (j >= i) return;
    unsigned a = e / Q_;
    unsigned k = e % Q_;
    Jt[(size_t)ij * BLKF + k * ROWP + a] = J[idx];
}

// ---- main: contrib gather + log_softmax + weighted ll accumulate ----
// MODE 0: use Jt + seqsT (fast). MODE 1: direct J + seqsT. MODE 2: direct J + direct seqs.
template <int MODE>
__global__ __launch_bounds__(256) void k_main(const float* __restrict__ Jt,
                                              const float* __restrict__ J,
                                              const float* __restrict__ h,
                                              const int* __restrict__ seqsT,
                                              const int* __restrict__ seqs,
                                              const float* __restrict__ weights,
                                              float* __restrict__ acc) {
    const int i = blockIdx.x >> 5;                        // 32 blocks per i
    const int b = ((blockIdx.x & 31) << 8) + threadIdx.x; // [0, 8192)

    float l[21];
    const float* hp = h + i * Q_;
#pragma unroll
    for (int a = 0; a < 21; ++a) l[a] = hp[a];

    for (int j = 0; j < i; ++j) {
        int k;
        if (MODE < 2) k = seqsT[j * M_ + b];
        else          k = seqs[b * L_ + j];

        if (MODE == 0) {
            const float* row = Jt + (size_t)(i * L_ + j) * BLKF + k * ROWP;
            const float4* r4 = reinterpret_cast<const float4*>(row);
            float4 v0 = r4[0], v1 = r4[1], v2 = r4[2], v3 = r4[3], v4 = r4[4];
            float v20 = row[20];
            l[0] += v0.x;  l[1] += v0.y;  l[2] += v0.z;  l[3] += v0.w;
            l[4] += v1.x;  l[5] += v1.y;  l[6] += v1.z;  l[7] += v1.w;
            l[8] += v2.x;  l[9] += v2.y;  l[10] += v2.z; l[11] += v2.w;
            l[12] += v3.x; l[13] += v3.y; l[14] += v3.z; l[15] += v3.w;
            l[16] += v4.x; l[17] += v4.y; l[18] += v4.z; l[19] += v4.w;
            l[20] += v20;
        } else {
            const float* base = J + (size_t)(i * L_ + j) * QQ + k;
#pragma unroll
            for (int a = 0; a < 21; ++a) l[a] += base[a * Q_];
        }
    }

    // log-softmax + label gather
    int lbl;
    if (MODE < 2) lbl = seqsT[i * M_ + b];
    else          lbl = seqs[b * L_ + i];

    float m = l[0];
#pragma unroll
    for (int a = 1; a < 21; ++a) m = fmaxf(m, l[a]);
    float s = 0.f;
    float lv = l[0];
#pragma unroll
    for (int a = 0; a < 21; ++a) {
        s += __expf(l[a] - m);
        if (a > 0) lv = (a == lbl) ? l[a] : lv;
    }
    float ll = (lv - m) - __logf(s);
    float contrib = weights[b] * ll;

    float r = block_reduce_sum(contrib);
    if (threadIdx.x == 0) atomicAdd(&acc[1], r);
}

// ---- finalize ----
__global__ void k_final(const float* __restrict__ acc, float* __restrict__ out) {
    if (threadIdx.x == 0 && blockIdx.x == 0) {
        float wsum = fmaxf(acc[0], 1e-12f);
        float nll = -acc[1] / wsum;
        float reg = 0.5e-6f * acc[2] + 0.5e-4f * acc[3];
        out[0] = nll + reg;
        out[1] = nll;
        out[2] = reg;
    }
}

extern "C" void kernel_launch(void* const* d_in, const int* in_sizes, int n_in,
                              void* d_out, int out_size, void* d_ws, size_t ws_size,
                              hipStream_t stream) {
    const int*   seqs    = (const int*)d_in[0];
    const float* weights = (const float*)d_in[1];
    const float* h       = (const float*)d_in[2];
    const float* J       = (const float*)d_in[3];
    float* out = (float*)d_out;

    char* ws = (char*)d_ws;
    float* acc   = (float*)ws;
    int*   seqsT = (int*)(ws + 256);
    float* Jt    = (float*)(ws + 256 + (size_t)L_ * M_ * sizeof(int));

    const size_t need_seqt = 256 + (size_t)L_ * M_ * sizeof(int);
    const size_t need_full = need_seqt + (size_t)L_ * L_ * BLKF * sizeof(float);
    int mode = (ws_size >= need_full) ? 0 : ((ws_size >= need_seqt) ? 1 : 2);

    hipMemsetAsync(d_ws, 0, 64, stream);

    k_wsum_h2<<<1, 256, 0, stream>>>(weights, h, acc);
    k_regJ<<<2048, 256, 0, stream>>>(J, acc);

    if (mode <= 1) k_transpose_seqs<<<L_, 256, 0, stream>>>(seqs, seqsT);
    if (mode == 0) {
        const unsigned nJ = (unsigned)L_ * L_ * QQ;
        k_transpose_J<<<(nJ + 255) / 256, 256, 0, stream>>>(J, Jt);
    }

    dim3 grid(L_ * (M_ / 256));  // 8192 blocks, 32 per i
    switch (mode) {
        case 0: k_main<0><<<grid, 256, 0, stream>>>(Jt, J, h, seqsT, seqs, weights, acc); break;
        case 1: k_main<1><<<grid, 256, 0, stream>>>(Jt, J, h, seqsT, seqs, weights, acc); break;
        default: k_main<2><<<grid, 256, 0, stream>>>(Jt, J, h, seqsT, seqs, weights, acc); break;
    }

    k_final<<<1, 1, 0, stream>>>(acc, out);
}

// Round 2
// 1087.499 us; speedup vs baseline: 1.4947x; 1.4947x over previous
//
#include <hip/hip_runtime.h>
#include <cstdint>
#include <cstddef>

// Problem constants
#define L_   256
#define Q_   21
#define M_   8192
#define QQ   441
#define JCH  16          // j-blocks staged per barrier in k_main
// Jt block layout: 21 rows (k) x 24 bf16 (a=0..20 + 3 pad), row stride 48 B,
// block = 1024 B = 256 dwords. Jt total = 256*256 blocks * 1024 B = 64 MiB.

// ws layout:
//   [0..63]    float acc: [0]=wsum [1]=ll_sum [2]=h2_sum [3]=J2_sum
//   [256..+8MiB)   seqsT (L*M int32)
//   [256+8MiB..)   Jt (bf16, packed dwords)

__device__ __forceinline__ float block_reduce_sum(float v) {
    __shared__ float s[256];
    int t = threadIdx.x;
    s[t] = v;
    __syncthreads();
#pragma unroll
    for (int o = 128; o > 0; o >>= 1) {
        if (t < o) s[t] += s[t + o];
        __syncthreads();
    }
    return s[0];
}

__device__ __forceinline__ unsigned bf16_rne(float x) {
    unsigned u = __float_as_uint(x);
    u += 0x7fffu + ((u >> 16) & 1u);
    return u >> 16;
}

// ---- weights sum + h^2 sum (single block; tiny) ----
__global__ void k_wsum_h2(const float* __restrict__ w, const float* __restrict__ h,
                          float* __restrict__ acc) {
    int t = threadIdx.x;
    float v = 0.f;
    for (int x = t; x < M_; x += 256) v += w[x];
    float r = block_reduce_sum(v);
    if (t == 0) acc[0] = r;
    float v2 = 0.f;
    for (int x = t; x < L_ * Q_; x += 256) { float y = h[x]; v2 += y * y; }
    float r2 = block_reduce_sum(v2);
    if (t == 0) acc[2] = r2;
}

// ---- seqs (M,L) -> seqsT (L,M) ----
__global__ void k_transpose_seqs(const int* __restrict__ seqs, int* __restrict__ seqsT) {
    int j = blockIdx.x;
    for (int b = threadIdx.x; b < M_; b += 256) {
        seqsT[j * M_ + b] = seqs[b * L_ + j];
    }
}

// ---- J (i,j,a,k) fp32 -> Jt (i,j,k,a) bf16 rows padded to 24, + fused reg_J ----
// grid = 65536 blocks (one per (i,j)), 256 threads; each thread emits 1 dword (2 bf16)
__global__ void k_prep_J(const float* __restrict__ J, unsigned* __restrict__ Jt,
                         float* __restrict__ acc) {
    int ij = blockIdx.x;
    int j = ij & (L_ - 1);
    int i = ij >> 8;
    if (j >= i) return;   // upper triangle never read by k_main

    int t = threadIdx.x;
    int k  = t / 12;           // row (0..21); 12 dwords (48 B) per row
    int a0 = 2 * (t - 12 * k); // even element index in row (0..22)

    float v2 = 0.f;
    unsigned outw = 0;
    if (k < Q_) {
        const float* blk = J + (size_t)ij * QQ;
        float x0 = (a0 + 0 < Q_) ? blk[(a0 + 0) * Q_ + k] : 0.f;
        float x1 = (a0 + 1 < Q_) ? blk[(a0 + 1) * Q_ + k] : 0.f;
        v2 = x0 * x0 + x1 * x1;
        outw = bf16_rne(x0) | (bf16_rne(x1) << 16);
    }
    Jt[(size_t)ij * 256 + t] = outw;

    float r = block_reduce_sum(v2);
    if (t == 0) atomicAdd(&acc[3], r);
}

// ---- main: LDS-staged bf16 gather + log_softmax + weighted ll ----
__global__ __launch_bounds__(256, 6) void k_main(const unsigned* __restrict__ Jt,
                                                 const float* __restrict__ h,
                                                 const int* __restrict__ seqsT,
                                                 const float* __restrict__ weights,
                                                 float* __restrict__ acc) {
    __shared__ unsigned sJ[JCH * 256];   // 16 KiB: JCH j-blocks x 256 dwords

    const int bid = blockIdx.x;
    const int i = (L_ - 1) - (bid >> 5);              // heavy blocks first
    const int b = ((bid & 31) << 8) + threadIdx.x;    // [0, 8192)

    float l[21];
    const float* hp = h + i * Q_;
#pragma unroll
    for (int a = 0; a < 21; ++a) l[a] = hp[a];

    const unsigned* Jrow = Jt + (size_t)i * (256 * 256);  // dwords of row i

    for (int j0 = 0; j0 < i; j0 += JCH) {
        // stage JCH blocks (j0..j0+JCH-1); j0 <= 240 so always in-bounds
        {
            const uint4* src = reinterpret_cast<const uint4*>(Jrow + j0 * 256);
            uint4* dst = reinterpret_cast<uint4*>(sJ);
#pragma unroll
            for (int n = 0; n < (JCH * 64) / 256; ++n) {
                dst[n * 256 + threadIdx.x] = src[n * 256 + threadIdx.x];
            }
        }
        __syncthreads();

        // prefetch the k indices for this stage
        int ks[JCH];
#pragma unroll
        for (int jj = 0; jj < JCH; ++jj) {
            ks[jj] = seqsT[(j0 + jj) * M_ + b];
        }

        const int nj = min(i - j0, JCH);
#pragma unroll
        for (int jj = 0; jj < JCH; ++jj) {
            if (jj >= nj) break;
            const unsigned* row = sJ + jj * 256 + ks[jj] * 12;  // 48 B rows
            uint4 r0 = *reinterpret_cast<const uint4*>(row);
            uint4 r1 = *reinterpret_cast<const uint4*>(row + 4);
            uint4 r2 = *reinterpret_cast<const uint4*>(row + 8);
            // dword n holds bf16 elems 2n (low) and 2n+1 (high)
            l[0]  += __uint_as_float(r0.x << 16); l[1]  += __uint_as_float(r0.x & 0xffff0000u);
            l[2]  += __uint_as_float(r0.y << 16); l[3]  += __uint_as_float(r0.y & 0xffff0000u);
            l[4]  += __uint_as_float(r0.z << 16); l[5]  += __uint_as_float(r0.z & 0xffff0000u);
            l[6]  += __uint_as_float(r0.w << 16); l[7]  += __uint_as_float(r0.w & 0xffff0000u);
            l[8]  += __uint_as_float(r1.x << 16); l[9]  += __uint_as_float(r1.x & 0xffff0000u);
            l[10] += __uint_as_float(r1.y << 16); l[11] += __uint_as_float(r1.y & 0xffff0000u);
            l[12] += __uint_as_float(r1.z << 16); l[13] += __uint_as_float(r1.z & 0xffff0000u);
            l[14] += __uint_as_float(r1.w << 16); l[15] += __uint_as_float(r1.w & 0xffff0000u);
            l[16] += __uint_as_float(r2.x << 16); l[17] += __uint_as_float(r2.x & 0xffff0000u);
            l[18] += __uint_as_float(r2.y << 16); l[19] += __uint_as_float(r2.y & 0xffff0000u);
            l[20] += __uint_as_float(r2.z << 16);
        }
        __syncthreads();
    }

    // log-softmax + label gather
    int lbl = seqsT[i * M_ + b];
    float m = l[0];
#pragma unroll
    for (int a = 1; a < 21; ++a) m = fmaxf(m, l[a]);
    float s = 0.f;
    float lv = l[0];
#pragma unroll
    for (int a = 0; a < 21; ++a) {
        s += __expf(l[a] - m);
        if (a > 0) lv = (a == lbl) ? l[a] : lv;
    }
    float ll = (lv - m) - __logf(s);
    float contrib = weights[b] * ll;

    float r = block_reduce_sum(contrib);
    if (threadIdx.x == 0) atomicAdd(&acc[1], r);
}

// ---- finalize ----
__global__ void k_final(const float* __restrict__ acc, float* __restrict__ out) {
    if (threadIdx.x == 0 && blockIdx.x == 0) {
        float wsum = fmaxf(acc[0], 1e-12f);
        float nll = -acc[1] / wsum;
        float reg = 0.5e-6f * acc[2] + 0.5e-4f * acc[3];
        out[0] = nll + reg;
        out[1] = nll;
        out[2] = reg;
    }
}

extern "C" void kernel_launch(void* const* d_in, const int* in_sizes, int n_in,
                              void* d_out, int out_size, void* d_ws, size_t ws_size,
                              hipStream_t stream) {
    const int*   seqs    = (const int*)d_in[0];
    const float* weights = (const float*)d_in[1];
    const float* h       = (const float*)d_in[2];
    const float* J       = (const float*)d_in[3];
    float* out = (float*)d_out;

    char* ws = (char*)d_ws;
    float*    acc   = (float*)ws;
    int*      seqsT = (int*)(ws + 256);
    unsigned* Jt    = (unsigned*)(ws + 256 + (size_t)L_ * M_ * sizeof(int));

    hipMemsetAsync(d_ws, 0, 64, stream);

    k_wsum_h2<<<1, 256, 0, stream>>>(weights, h, acc);
    k_transpose_seqs<<<L_, 256, 0, stream>>>(seqs, seqsT);
    k_prep_J<<<L_ * L_, 256, 0, stream>>>(J, Jt, acc);

    k_main<<<L_ * (M_ / 256), 256, 0, stream>>>(Jt, h, seqsT, weights, acc);

    k_final<<<1, 1, 0, stream>>>(acc, out);
}

// Round 3
// 836.323 us; speedup vs baseline: 1.9436x; 1.3003x over previous
//
#include <hip/hip_runtime.h>
#include <cstdint>
#include <cstddef>

// Problem constants
#define L_   256
#define Q_   21
#define M_   8192
#define QQ   441
#define JCH  32            // j-blocks staged per barrier in k_main
#define SCALE    32.0f     // J scaled by 32 before fp8 quantization
#define INVSCALE 0.03125f

// Jt block layout (per (i,j)): 21 rows (k = symbol), each row 24 B =
// 21 fp8(e4m3, J*32) elems a=0..20 + 3 zero pad. Row stride 6 dwords.
// Block padded to 512 B (128 dwords). Jt total = 65536 * 512 B = 32 MiB.
//
// ws layout:
//   [0..255]       float acc: [0]=wsum [1]=ll_sum [2]=h2_sum [3]=J2_sum
//   [256..+2MiB)   seqsP: packed symbols, dword[jq*M + b] = k(4jq..4jq+3) bytes
//   [256+2MiB..)   Jt (fp8 blocks)

typedef float v2f __attribute__((ext_vector_type(2)));

__device__ __forceinline__ float block_reduce_sum(float v) {
    __shared__ float s[256];
    int t = threadIdx.x;
    s[t] = v;
    __syncthreads();
#pragma unroll
    for (int o = 128; o > 0; o >>= 1) {
        if (t < o) s[t] += s[t + o];
        __syncthreads();
    }
    return s[0];
}

__device__ __forceinline__ float wave_reduce_sum(float v) {
#pragma unroll
    for (int o = 32; o > 0; o >>= 1) v += __shfl_down(v, o, 64);
    return v;
}

// ---- weights sum + h^2 sum (single block; tiny) ----
__global__ void k_wsum_h2(const float* __restrict__ w, const float* __restrict__ h,
                          float* __restrict__ acc) {
    int t = threadIdx.x;
    float v = 0.f;
    for (int x = t; x < M_; x += 256) v += w[x];
    float r = block_reduce_sum(v);
    if (t == 0) acc[0] = r;
    float v2 = 0.f;
    for (int x = t; x < L_ * Q_; x += 256) { float y = h[x]; v2 += y * y; }
    float r2 = block_reduce_sum(v2);
    if (t == 0) acc[2] = r2;
}

// ---- seqs (M,L) -> seqsP packed bytes: dword[jq*M + b] holds j=4jq..4jq+3 ----
__global__ void k_pack_seqs(const int* __restrict__ seqs, unsigned* __restrict__ seqsP) {
    int b = blockIdx.x * 256 + threadIdx.x;   // 8192 threads
    const int4* row = reinterpret_cast<const int4*>(seqs + (size_t)b * L_);
#pragma unroll 4
    for (int jq = 0; jq < L_ / 4; ++jq) {
        int4 v = row[jq];
        unsigned p = (unsigned)(v.x & 255) | ((unsigned)(v.y & 255) << 8) |
                     ((unsigned)(v.z & 255) << 16) | ((unsigned)(v.w & 255) << 24);
        seqsP[jq * M_ + b] = p;
    }
}

// ---- J (i,j,a,k) fp32 -> Jt fp8 blocks + fused reg_J; one block per (i,j) ----
__global__ void k_prep_J(const float* __restrict__ J, unsigned* __restrict__ Jt,
                         float* __restrict__ acc) {
    int ij = blockIdx.x;
    int j = ij & (L_ - 1);
    int i = ij >> 8;
    if (j >= i) return;   // upper triangle never read

    __shared__ float sB[QQ];
    __shared__ float swr[4];
    int t = threadIdx.x;
    const float* blk = J + (size_t)ij * QQ;
    for (int x = t; x < QQ; x += 256) sB[x] = blk[x];
    __syncthreads();

    float v2 = 0.f;
    unsigned outw = 0;
    if (t < 128) {
        int k  = t / 6;        // row 0..21 (t<126 valid)
        int dw = t - 6 * k;    // dword within row
        int a0 = dw * 4;
        if (k < Q_) {
            float x0 = (a0 + 0 < Q_) ? sB[(a0 + 0) * Q_ + k] : 0.f;
            float x1 = (a0 + 1 < Q_) ? sB[(a0 + 1) * Q_ + k] : 0.f;
            float x2 = (a0 + 2 < Q_) ? sB[(a0 + 2) * Q_ + k] : 0.f;
            float x3 = (a0 + 3 < Q_) ? sB[(a0 + 3) * Q_ + k] : 0.f;
            v2 = x0 * x0 + x1 * x1 + x2 * x2 + x3 * x3;
            outw = (unsigned)__builtin_amdgcn_cvt_pk_fp8_f32(x0 * SCALE, x1 * SCALE, 0, false);
            outw = (unsigned)__builtin_amdgcn_cvt_pk_fp8_f32(x2 * SCALE, x3 * SCALE, (int)outw, true);
        }
        Jt[(size_t)ij * 128 + t] = outw;
    }
    float wr = wave_reduce_sum(v2);
    if ((t & 63) == 0) swr[t >> 6] = wr;
    __syncthreads();
    if (t == 0) atomicAdd(&acc[3], swr[0] + swr[1] + swr[2] + swr[3]);
}

// ---- main: LDS-staged fp8 gather + log_softmax + weighted ll ----
__global__ __launch_bounds__(256, 4) void k_main(const unsigned* __restrict__ Jt,
                                                 const float* __restrict__ h,
                                                 const unsigned* __restrict__ seqsP,
                                                 const float* __restrict__ weights,
                                                 float* __restrict__ acc) {
    __shared__ unsigned sJ[JCH * 128];   // 16 KiB: JCH blocks x 128 dwords

    const int bid = blockIdx.x;
    const int i = (L_ - 1) - (bid >> 5);              // heavy blocks first
    const int b = ((bid & 31) << 8) + threadIdx.x;    // [0, 8192)

    // packed accumulators: acc2[m] covers logits a=2m, 2m+1 (scaled by SCALE)
    v2f acc2[11];
    const float* hp = h + i * Q_;
#pragma unroll
    for (int m = 0; m < 10; ++m) { acc2[m].x = hp[2*m] * SCALE; acc2[m].y = hp[2*m+1] * SCALE; }
    acc2[10].x = hp[20] * SCALE; acc2[10].y = 0.f;

    const unsigned* Jrow = Jt + (size_t)i * (256 * 128);  // dwords of row i

    for (int j0 = 0; j0 < i; j0 += JCH) {
        // stage JCH fp8 blocks: JCH*128 dwords = 1024 uint4, 4 per thread
        {
            const uint4* src = reinterpret_cast<const uint4*>(Jrow + j0 * 128);
            uint4* dst = reinterpret_cast<uint4*>(sJ);
#pragma unroll
            for (int n = 0; n < (JCH * 32) / 256; ++n) {
                dst[n * 256 + threadIdx.x] = src[n * 256 + threadIdx.x];
            }
        }
        __syncthreads();

        // packed indices for this stage: 8 dwords = 32 symbols
        unsigned idxw[JCH / 4];
#pragma unroll
        for (int q = 0; q < JCH / 4; ++q) {
            idxw[q] = seqsP[((j0 >> 2) + q) * M_ + b];
        }

        const int nj = min(i - j0, JCH);
#pragma unroll
        for (int jj = 0; jj < JCH; ++jj) {
            if (jj >= nj) break;
            const unsigned k = (idxw[jj >> 2] >> ((jj & 3) * 8)) & 255u;
            // row: block jj, row k -> uint2 index (jj*128 + k*6)/2
            const uint2* r = reinterpret_cast<const uint2*>(sJ) + (jj * 64 + k * 3);
            uint2 d0 = r[0], d1 = r[1], d2 = r[2];
            acc2[0]  += __builtin_amdgcn_cvt_pk_f32_fp8(d0.x, false);
            acc2[1]  += __builtin_amdgcn_cvt_pk_f32_fp8(d0.x, true);
            acc2[2]  += __builtin_amdgcn_cvt_pk_f32_fp8(d0.y, false);
            acc2[3]  += __builtin_amdgcn_cvt_pk_f32_fp8(d0.y, true);
            acc2[4]  += __builtin_amdgcn_cvt_pk_f32_fp8(d1.x, false);
            acc2[5]  += __builtin_amdgcn_cvt_pk_f32_fp8(d1.x, true);
            acc2[6]  += __builtin_amdgcn_cvt_pk_f32_fp8(d1.y, false);
            acc2[7]  += __builtin_amdgcn_cvt_pk_f32_fp8(d1.y, true);
            acc2[8]  += __builtin_amdgcn_cvt_pk_f32_fp8(d2.x, false);
            acc2[9]  += __builtin_amdgcn_cvt_pk_f32_fp8(d2.x, true);
            acc2[10] += __builtin_amdgcn_cvt_pk_f32_fp8(d2.y, false);
        }
        __syncthreads();
    }

    // unpack logits
    float l[21];
#pragma unroll
    for (int m = 0; m < 10; ++m) { l[2*m] = acc2[m].x * INVSCALE; l[2*m+1] = acc2[m].y * INVSCALE; }
    l[20] = acc2[10].x * INVSCALE;

    // label gather from packed seqs
    unsigned lw = seqsP[(i >> 2) * M_ + b];
    int lbl = (int)((lw >> ((i & 3) * 8)) & 255u);

    float m = l[0];
#pragma unroll
    for (int a = 1; a < 21; ++a) m = fmaxf(m, l[a]);
    float s = 0.f;
    float lv = l[0];
#pragma unroll
    for (int a = 0; a < 21; ++a) {
        s += __expf(l[a] - m);
        if (a > 0) lv = (a == lbl) ? l[a] : lv;
    }
    float ll = (lv - m) - __logf(s);
    float contrib = weights[b] * ll;

    float r = block_reduce_sum(contrib);
    if (threadIdx.x == 0) atomicAdd(&acc[1], r);
}

// ---- finalize ----
__global__ void k_final(const float* __restrict__ acc, float* __restrict__ out) {
    if (threadIdx.x == 0 && blockIdx.x == 0) {
        float wsum = fmaxf(acc[0], 1e-12f);
        float nll = -acc[1] / wsum;
        float reg = 0.5e-6f * acc[2] + 0.5e-4f * acc[3];
        out[0] = nll + reg;
        out[1] = nll;
        out[2] = reg;
    }
}

extern "C" void kernel_launch(void* const* d_in, const int* in_sizes, int n_in,
                              void* d_out, int out_size, void* d_ws, size_t ws_size,
                              hipStream_t stream) {
    const int*   seqs    = (const int*)d_in[0];
    const float* weights = (const float*)d_in[1];
    const float* h       = (const float*)d_in[2];
    const float* J       = (const float*)d_in[3];
    float* out = (float*)d_out;

    char* ws = (char*)d_ws;
    float*    acc   = (float*)ws;
    unsigned* seqsP = (unsigned*)(ws + 256);
    unsigned* Jt    = (unsigned*)(ws + 256 + (size_t)(L_ / 4) * M_ * sizeof(unsigned));

    hipMemsetAsync(d_ws, 0, 64, stream);

    k_wsum_h2<<<1, 256, 0, stream>>>(weights, h, acc);
    k_pack_seqs<<<M_ / 256, 256, 0, stream>>>(seqs, seqsP);
    k_prep_J<<<L_ * L_, 256, 0, stream>>>(J, Jt, acc);

    k_main<<<L_ * (M_ / 256), 256, 0, stream>>>(Jt, h, seqsP, weights, acc);

    k_final<<<1, 1, 0, stream>>>(acc, out);
}

// Round 4
// 453.269 us; speedup vs baseline: 3.5861x; 1.8451x over previous
//
#include <hip/hip_runtime.h>
#include <cstdint>
#include <cstddef>

// Problem constants
#define L_   256
#define Q_   21
#define M_   8192
#define QQ   441
#define JCH  32            // j-blocks staged per barrier in k_main
#define SCALE    32.0f     // J scaled by 32 before fp8 quantization
#define INVSCALE 0.03125f
#define NPAIR ((L_ * (L_ - 1)) / 2)   // 32640 valid (i,j) pairs
#define PREPB 2048         // grid for k_prep_J

// Jt block layout (per (i,j)): 21 rows (k = symbol), each row 24 B =
// 21 fp8(e4m3, J*32) elems a=0..20 + 3 zero pad. Row stride 6 dwords.
// Block padded to 512 B (128 dwords). Jt total = 65536 * 512 B = 32 MiB.
//
// ws layout:
//   [0..511]       float acc: [0]=wsum [1]=ll_sum [2]=h2_sum [4..67]=J2 slots
//   [512..+2MiB)   seqsP: packed symbols, dword[jq*M + b] = k(4jq..4jq+3) bytes
//   [512+2MiB..)   Jt (fp8 blocks)

typedef float v2f __attribute__((ext_vector_type(2)));

__device__ __forceinline__ float block_reduce_sum(float v) {
    __shared__ float s[256];
    int t = threadIdx.x;
    s[t] = v;
    __syncthreads();
#pragma unroll
    for (int o = 128; o > 0; o >>= 1) {
        if (t < o) s[t] += s[t + o];
        __syncthreads();
    }
    return s[0];
}

// ---- weights sum + h^2 sum (single block; tiny) ----
__global__ void k_wsum_h2(const float* __restrict__ w, const float* __restrict__ h,
                          float* __restrict__ acc) {
    int t = threadIdx.x;
    float v = 0.f;
    for (int x = t; x < M_; x += 256) v += w[x];
    float r = block_reduce_sum(v);
    if (t == 0) acc[0] = r;
    float v2 = 0.f;
    for (int x = t; x < L_ * Q_; x += 256) { float y = h[x]; v2 += y * y; }
    float r2 = block_reduce_sum(v2);
    if (t == 0) acc[2] = r2;
}

// ---- seqs (M,L) -> seqsP packed bytes: dword[jq*M + b] holds j=4jq..4jq+3 ----
__global__ void k_pack_seqs(const int* __restrict__ seqs, unsigned* __restrict__ seqsP) {
    int b = blockIdx.x * 256 + threadIdx.x;   // 8192 threads
    const int4* row = reinterpret_cast<const int4*>(seqs + (size_t)b * L_);
#pragma unroll 4
    for (int jq = 0; jq < L_ / 4; ++jq) {
        int4 v = row[jq];
        unsigned p = (unsigned)(v.x & 255) | ((unsigned)(v.y & 255) << 8) |
                     ((unsigned)(v.z & 255) << 16) | ((unsigned)(v.w & 255) << 24);
        seqsP[jq * M_ + b] = p;
    }
}

// ---- J fp32 -> Jt fp8 + fused reg_J; grid-stride over valid (i,j) pairs ----
__global__ __launch_bounds__(256) void k_prep_J(const float* __restrict__ J,
                                                unsigned* __restrict__ Jt,
                                                float* __restrict__ acc) {
    __shared__ float sB[QQ];
    int t = threadIdx.x;
    float v2acc = 0.f;

    for (int n = blockIdx.x; n < NPAIR; n += PREPB) {
        // invert triangular index: i s.t. T(i)=i(i-1)/2 <= n < T(i)+i
        int i = (int)((1.0f + sqrtf(8.0f * (float)n + 1.0f)) * 0.5f);
        while (i * (i - 1) / 2 > n) --i;
        while (i * (i - 1) / 2 + i <= n) ++i;
        int j = n - i * (i - 1) / 2;            // j < i
        const size_t ij = (size_t)i * L_ + j;

        const float* blk = J + ij * QQ;
        for (int x = t; x < QQ; x += 256) sB[x] = blk[x];
        __syncthreads();

        if (t < 128) {
            int k  = t / 6;        // row 0..21 (t<126 valid)
            int dw = t - 6 * k;    // dword within row
            int a0 = dw * 4;
            unsigned outw = 0;
            if (k < Q_) {
                float x0 = (a0 + 0 < Q_) ? sB[(a0 + 0) * Q_ + k] : 0.f;
                float x1 = (a0 + 1 < Q_) ? sB[(a0 + 1) * Q_ + k] : 0.f;
                float x2 = (a0 + 2 < Q_) ? sB[(a0 + 2) * Q_ + k] : 0.f;
                float x3 = (a0 + 3 < Q_) ? sB[(a0 + 3) * Q_ + k] : 0.f;
                v2acc += x0 * x0 + x1 * x1 + x2 * x2 + x3 * x3;
                outw = (unsigned)__builtin_amdgcn_cvt_pk_fp8_f32(x0 * SCALE, x1 * SCALE, 0, false);
                outw = (unsigned)__builtin_amdgcn_cvt_pk_fp8_f32(x2 * SCALE, x3 * SCALE, (int)outw, true);
            }
            Jt[ij * 128 + t] = outw;
        }
        __syncthreads();
    }

    float r = block_reduce_sum(v2acc);
    if (t == 0) atomicAdd(&acc[4 + (blockIdx.x & 63)], r);
}

// ---- main: LDS-staged fp8 gather + log_softmax + weighted ll ----
__global__ __launch_bounds__(256, 4) void k_main(const unsigned* __restrict__ Jt,
                                                 const float* __restrict__ h,
                                                 const unsigned* __restrict__ seqsP,
                                                 const float* __restrict__ weights,
                                                 float* __restrict__ acc) {
    __shared__ unsigned sJ[JCH * 128];   // 16 KiB: JCH blocks x 128 dwords

    const int bid = blockIdx.x;
    const int i = (L_ - 1) - (bid >> 5);              // heavy blocks first
    const int b = ((bid & 31) << 8) + threadIdx.x;    // [0, 8192)

    // packed accumulators: acc2[m] covers logits a=2m, 2m+1 (scaled by SCALE)
    v2f acc2[11];
    const float* hp = h + i * Q_;
#pragma unroll
    for (int m = 0; m < 10; ++m) { acc2[m].x = hp[2*m] * SCALE; acc2[m].y = hp[2*m+1] * SCALE; }
    acc2[10].x = hp[20] * SCALE; acc2[10].y = 0.f;

    const unsigned* Jrow = Jt + (size_t)i * (256 * 128);  // dwords of row i

    for (int j0 = 0; j0 < i; j0 += JCH) {
        // stage JCH fp8 blocks: JCH*128 dwords = 1024 uint4, 4 per thread
        {
            const uint4* src = reinterpret_cast<const uint4*>(Jrow + j0 * 128);
            uint4* dst = reinterpret_cast<uint4*>(sJ);
#pragma unroll
            for (int n = 0; n < (JCH * 32) / 256; ++n) {
                dst[n * 256 + threadIdx.x] = src[n * 256 + threadIdx.x];
            }
        }
        __syncthreads();

        // packed indices for this stage: 8 dwords = 32 symbols
        unsigned idxw[JCH / 4];
#pragma unroll
        for (int q = 0; q < JCH / 4; ++q) {
            idxw[q] = seqsP[((j0 >> 2) + q) * M_ + b];
        }

        const int nj = min(i - j0, JCH);
#pragma unroll
        for (int jj = 0; jj < JCH; ++jj) {
            if (jj >= nj) break;
            const unsigned k = (idxw[jj >> 2] >> ((jj & 3) * 8)) & 255u;
            // row: block jj, row k -> uint2 index (jj*128 + k*6)/2
            const uint2* r = reinterpret_cast<const uint2*>(sJ) + (jj * 64 + k * 3);
            uint2 d0 = r[0], d1 = r[1], d2 = r[2];
            acc2[0]  += __builtin_amdgcn_cvt_pk_f32_fp8(d0.x, false);
            acc2[1]  += __builtin_amdgcn_cvt_pk_f32_fp8(d0.x, true);
            acc2[2]  += __builtin_amdgcn_cvt_pk_f32_fp8(d0.y, false);
            acc2[3]  += __builtin_amdgcn_cvt_pk_f32_fp8(d0.y, true);
            acc2[4]  += __builtin_amdgcn_cvt_pk_f32_fp8(d1.x, false);
            acc2[5]  += __builtin_amdgcn_cvt_pk_f32_fp8(d1.x, true);
            acc2[6]  += __builtin_amdgcn_cvt_pk_f32_fp8(d1.y, false);
            acc2[7]  += __builtin_amdgcn_cvt_pk_f32_fp8(d1.y, true);
            acc2[8]  += __builtin_amdgcn_cvt_pk_f32_fp8(d2.x, false);
            acc2[9]  += __builtin_amdgcn_cvt_pk_f32_fp8(d2.x, true);
            acc2[10] += __builtin_amdgcn_cvt_pk_f32_fp8(d2.y, false);
        }
        __syncthreads();
    }

    // unpack logits
    float l[21];
#pragma unroll
    for (int m = 0; m < 10; ++m) { l[2*m] = acc2[m].x * INVSCALE; l[2*m+1] = acc2[m].y * INVSCALE; }
    l[20] = acc2[10].x * INVSCALE;

    // label gather from packed seqs
    unsigned lw = seqsP[(i >> 2) * M_ + b];
    int lbl = (int)((lw >> ((i & 3) * 8)) & 255u);

    float m = l[0];
#pragma unroll
    for (int a = 1; a < 21; ++a) m = fmaxf(m, l[a]);
    float s = 0.f;
    float lv = l[0];
#pragma unroll
    for (int a = 0; a < 21; ++a) {
        s += __expf(l[a] - m);
        if (a > 0) lv = (a == lbl) ? l[a] : lv;
    }
    float ll = (lv - m) - __logf(s);
    float contrib = weights[b] * ll;

    float r = block_reduce_sum(contrib);
    if (threadIdx.x == 0) atomicAdd(&acc[1], r);
}

// ---- finalize ----
__global__ void k_final(const float* __restrict__ acc, float* __restrict__ out) {
    if (threadIdx.x == 0 && blockIdx.x == 0) {
        float wsum = fmaxf(acc[0], 1e-12f);
        float nll = -acc[1] / wsum;
        float j2 = 0.f;
        for (int s = 0; s < 64; ++s) j2 += acc[4 + s];
        float reg = 0.5e-6f * acc[2] + 0.5e-4f * j2;
        out[0] = nll + reg;
        out[1] = nll;
        out[2] = reg;
    }
}

extern "C" void kernel_launch(void* const* d_in, const int* in_sizes, int n_in,
                              void* d_out, int out_size, void* d_ws, size_t ws_size,
                              hipStream_t stream) {
    const int*   seqs    = (const int*)d_in[0];
    const float* weights = (const float*)d_in[1];
    const float* h       = (const float*)d_in[2];
    const float* J       = (const float*)d_in[3];
    float* out = (float*)d_out;

    char* ws = (char*)d_ws;
    float*    acc   = (float*)ws;
    unsigned* seqsP = (unsigned*)(ws + 512);
    unsigned* Jt    = (unsigned*)(ws + 512 + (size_t)(L_ / 4) * M_ * sizeof(unsigned));

    hipMemsetAsync(d_ws, 0, 512, stream);

    k_wsum_h2<<<1, 256, 0, stream>>>(weights, h, acc);
    k_pack_seqs<<<M_ / 256, 256, 0, stream>>>(seqs, seqsP);
    k_prep_J<<<PREPB, 256, 0, stream>>>(J, Jt, acc);

    k_main<<<L_ * (M_ / 256), 256, 0, stream>>>(Jt, h, seqsP, weights, acc);

    k_final<<<1, 1, 0, stream>>>(acc, out);
}

// Round 5
// 423.880 us; speedup vs baseline: 3.8347x; 1.0693x over previous
//
#include <hip/hip_runtime.h>
#include <cstdint>
#include <cstddef>

// Problem constants
#define L_   256
#define Q_   21
#define M_   8192
#define QQ   441
#define JCH  32            // j-blocks staged per barrier in k_main
#define SCALE    32.0f     // J scaled by 32 before fp8 quantization
#define INVSCALE 0.03125f
#define NPAIR ((L_ * (L_ - 1)) / 2)   // 32640 valid (i,j) pairs
#define PREPB 8160         // prep blocks (4 pairs each)

// Jt block layout (per (i,j)): 21 rows (k = symbol), each row 24 B =
// 21 fp8(e4m3, J*32) elems a=0..20 + 3 zero pad. Row stride 6 dwords.
// Block padded to 512 B (128 dwords). Jt total = 65536 * 512 B = 32 MiB.
//
// ws layout (floats at base):
//   acc[0]=wsum  acc[2]=h2_sum
//   acc[4..259]   = 256 J2 partial slots
//   acc[260..387] = 128 ll partial slots
//   [2048 .. +2MiB)  seqsP: dword[jq*M + b] = symbols j=4jq..4jq+3 (bytes)
//   [2048+2MiB ..)   Jt (fp8 blocks)

typedef float v2f __attribute__((ext_vector_type(2)));

__device__ __forceinline__ float block_reduce_sum(float v) {
    __shared__ float s[256];
    int t = threadIdx.x;
    __syncthreads();           // guard against reuse hazard
    s[t] = v;
    __syncthreads();
#pragma unroll
    for (int o = 128; o > 0; o >>= 1) {
        if (t < o) s[t] += s[t + o];
        __syncthreads();
    }
    return s[0];
}

// ---- fused prep: J->fp8 transpose + reg_J, seqs pack, wsum + h2 ----
__global__ __launch_bounds__(256) void k_prep(const float* __restrict__ J,
                                              const int* __restrict__ seqs,
                                              const float* __restrict__ w,
                                              const float* __restrict__ h,
                                              unsigned* __restrict__ Jt,
                                              unsigned* __restrict__ seqsP,
                                              float* __restrict__ acc) {
    const int bid = blockIdx.x;
    const int t = threadIdx.x;

    if (bid < PREPB) {
        __shared__ float sB[QQ];
        float v2acc = 0.f;
#pragma unroll 1
        for (int q = 0; q < 4; ++q) {
            const int n = bid * 4 + q;
            // invert triangular index: i s.t. i(i-1)/2 <= n < i(i-1)/2 + i
            int i = (int)((1.0f + sqrtf(8.0f * (float)n + 1.0f)) * 0.5f);
            while (i * (i - 1) / 2 > n) --i;
            while (i * (i - 1) / 2 + i <= n) ++i;
            const int j = n - i * (i - 1) / 2;   // j < i
            const size_t ij = (size_t)i * L_ + j;

            const float* blk = J + ij * QQ;
            for (int x = t; x < QQ; x += 256) sB[x] = blk[x];
            __syncthreads();

            if (t < 128) {
                int k  = t / 6;        // row 0..21 (t<126 valid)
                int dw = t - 6 * k;    // dword within row
                int a0 = dw * 4;
                unsigned outw = 0;
                if (k < Q_) {
                    float x0 = (a0 + 0 < Q_) ? sB[(a0 + 0) * Q_ + k] : 0.f;
                    float x1 = (a0 + 1 < Q_) ? sB[(a0 + 1) * Q_ + k] : 0.f;
                    float x2 = (a0 + 2 < Q_) ? sB[(a0 + 2) * Q_ + k] : 0.f;
                    float x3 = (a0 + 3 < Q_) ? sB[(a0 + 3) * Q_ + k] : 0.f;
                    v2acc += x0 * x0 + x1 * x1 + x2 * x2 + x3 * x3;
                    outw = (unsigned)__builtin_amdgcn_cvt_pk_fp8_f32(x0 * SCALE, x1 * SCALE, 0, false);
                    outw = (unsigned)__builtin_amdgcn_cvt_pk_fp8_f32(x2 * SCALE, x3 * SCALE, (int)outw, true);
                }
                Jt[ij * 128 + t] = outw;
            }
            __syncthreads();
        }
        float r = block_reduce_sum(v2acc);
        if (t == 0) atomicAdd(&acc[4 + (bid & 255)], r);
    } else if (bid < PREPB + 32) {
        // pack seqs (M,L) -> seqsP: 32 blocks x 256 threads = 8192 rows
        const int b = (bid - PREPB) * 256 + t;
        const int4* row = reinterpret_cast<const int4*>(seqs + (size_t)b * L_);
#pragma unroll 4
        for (int jq = 0; jq < L_ / 4; ++jq) {
            int4 v = row[jq];
            unsigned p = (unsigned)(v.x & 255) | ((unsigned)(v.y & 255) << 8) |
                         ((unsigned)(v.z & 255) << 16) | ((unsigned)(v.w & 255) << 24);
            seqsP[jq * M_ + b] = p;
        }
    } else {
        // weights sum + h^2 sum (one block)
        float v = 0.f;
        for (int x = t; x < M_; x += 256) v += w[x];
        float r = block_reduce_sum(v);
        if (t == 0) acc[0] = r;
        float v2 = 0.f;
        for (int x = t; x < L_ * Q_; x += 256) { float y = h[x]; v2 += y * y; }
        float r2 = block_reduce_sum(v2);
        if (t == 0) acc[2] = r2;
    }
}

// ---- main: LDS-staged fp8 gather + log_softmax + weighted ll ----
__global__ __launch_bounds__(256, 8) void k_main(const unsigned* __restrict__ Jt,
                                                 const float* __restrict__ h,
                                                 const unsigned* __restrict__ seqsP,
                                                 const float* __restrict__ weights,
                                                 float* __restrict__ acc) {
    __shared__ unsigned sJ[JCH * 128];   // 16 KiB: JCH blocks x 128 dwords

    const int bid = blockIdx.x;
    const int i = (L_ - 1) - (bid >> 5);              // heavy blocks first
    const int b = ((bid & 31) << 8) + threadIdx.x;    // [0, 8192)

    // packed accumulators: acc2[m] covers logits a=2m, 2m+1 (scaled by SCALE)
    v2f acc2[11];
    const float* hp = h + i * Q_;
#pragma unroll
    for (int m = 0; m < 10; ++m) { acc2[m].x = hp[2*m] * SCALE; acc2[m].y = hp[2*m+1] * SCALE; }
    acc2[10].x = hp[20] * SCALE; acc2[10].y = 0.f;

    const unsigned* Jrow = Jt + (size_t)i * (256 * 128);  // dwords of row i

    for (int j0 = 0; j0 < i; j0 += JCH) {
        // stage JCH fp8 blocks: JCH*128 dwords = 1024 uint4, 4 per thread
        {
            const uint4* src = reinterpret_cast<const uint4*>(Jrow + j0 * 128);
            uint4* dst = reinterpret_cast<uint4*>(sJ);
#pragma unroll
            for (int n = 0; n < (JCH * 32) / 256; ++n) {
                dst[n * 256 + threadIdx.x] = src[n * 256 + threadIdx.x];
            }
        }
        __syncthreads();

        // packed indices for this stage: 8 dwords = 32 symbols
        unsigned idxw[JCH / 4];
#pragma unroll
        for (int q = 0; q < JCH / 4; ++q) {
            idxw[q] = seqsP[((j0 >> 2) + q) * M_ + b];
        }

        const int nj = min(i - j0, JCH);
#pragma unroll
        for (int jj = 0; jj < JCH; ++jj) {
            if (jj >= nj) break;
            const unsigned k = (idxw[jj >> 2] >> ((jj & 3) * 8)) & 255u;
            // row: block jj, row k -> uint2 index (jj*128 + k*6)/2
            const uint2* r = reinterpret_cast<const uint2*>(sJ) + (jj * 64 + k * 3);
            uint2 d0 = r[0], d1 = r[1], d2 = r[2];
            acc2[0]  += __builtin_amdgcn_cvt_pk_f32_fp8(d0.x, false);
            acc2[1]  += __builtin_amdgcn_cvt_pk_f32_fp8(d0.x, true);
            acc2[2]  += __builtin_amdgcn_cvt_pk_f32_fp8(d0.y, false);
            acc2[3]  += __builtin_amdgcn_cvt_pk_f32_fp8(d0.y, true);
            acc2[4]  += __builtin_amdgcn_cvt_pk_f32_fp8(d1.x, false);
            acc2[5]  += __builtin_amdgcn_cvt_pk_f32_fp8(d1.x, true);
            acc2[6]  += __builtin_amdgcn_cvt_pk_f32_fp8(d1.y, false);
            acc2[7]  += __builtin_amdgcn_cvt_pk_f32_fp8(d1.y, true);
            acc2[8]  += __builtin_amdgcn_cvt_pk_f32_fp8(d2.x, false);
            acc2[9]  += __builtin_amdgcn_cvt_pk_f32_fp8(d2.x, true);
            acc2[10] += __builtin_amdgcn_cvt_pk_f32_fp8(d2.y, false);
        }
        __syncthreads();
    }

    // unpack logits
    float l[21];
#pragma unroll
    for (int m = 0; m < 10; ++m) { l[2*m] = acc2[m].x * INVSCALE; l[2*m+1] = acc2[m].y * INVSCALE; }
    l[20] = acc2[10].x * INVSCALE;

    // label gather from packed seqs
    unsigned lw = seqsP[(i >> 2) * M_ + b];
    int lbl = (int)((lw >> ((i & 3) * 8)) & 255u);

    float m = l[0];
#pragma unroll
    for (int a = 1; a < 21; ++a) m = fmaxf(m, l[a]);
    float s = 0.f;
    float lv = l[0];
#pragma unroll
    for (int a = 0; a < 21; ++a) {
        s += __expf(l[a] - m);
        if (a > 0) lv = (a == lbl) ? l[a] : lv;
    }
    float ll = (lv - m) - __logf(s);
    float contrib = weights[b] * ll;

    float r = block_reduce_sum(contrib);
    if (threadIdx.x == 0) atomicAdd(&acc[260 + (bid & 127)], r);
}

// ---- finalize: reduce partial slots + compose outputs ----
__global__ void k_final(const float* __restrict__ acc, float* __restrict__ out) {
    int t = threadIdx.x;
    float j2p = acc[4 + t];                       // 256 J2 slots
    float j2 = block_reduce_sum(j2p);
    float llp = (t < 128) ? acc[260 + t] : 0.f;   // 128 ll slots
    float lls = block_reduce_sum(llp);
    if (t == 0) {
        float wsum = fmaxf(acc[0], 1e-12f);
        float nll = -lls / wsum;
        float reg = 0.5e-6f * acc[2] + 0.5e-4f * j2;
        out[0] = nll + reg;
        out[1] = nll;
        out[2] = reg;
    }
}

extern "C" void kernel_launch(void* const* d_in, const int* in_sizes, int n_in,
                              void* d_out, int out_size, void* d_ws, size_t ws_size,
                              hipStream_t stream) {
    const int*   seqs    = (const int*)d_in[0];
    const float* weights = (const float*)d_in[1];
    const float* h       = (const float*)d_in[2];
    const float* J       = (const float*)d_in[3];
    float* out = (float*)d_out;

    char* ws = (char*)d_ws;
    float*    acc   = (float*)ws;
    unsigned* seqsP = (unsigned*)(ws + 2048);
    unsigned* Jt    = (unsigned*)(ws + 2048 + (size_t)(L_ / 4) * M_ * sizeof(unsigned));

    hipMemsetAsync(d_ws, 0, 2048, stream);

    k_prep<<<PREPB + 33, 256, 0, stream>>>(J, seqs, weights, h, Jt, seqsP, acc);
    k_main<<<L_ * (M_ / 256), 256, 0, stream>>>(Jt, h, seqsP, weights, acc);
    k_final<<<1, 256, 0, stream>>>(acc, out);
}